// Round 1
// 229.531 us; speedup vs baseline: 1.0007x; 1.0007x over previous
//
#include <hip/hip_runtime.h>
#include <stdint.h>

// All buffers f32. Timed window carries ~164 us of harness poison fills
// (857 MB ws fill @ ~131 us + 219 MB out fill @ ~33 us, visible in rocprof
// every iteration); our 3 dispatches are the ~66 us remainder.
// Config history: r5 plain/CSPLIT4 = 231.0 | r4 = 233.6 | r7 nt/CSPLIT2 = 240.2
// -> plain stores (the 6.6 TB/s harness fill uses plain stores too), CSPLIT 4.
// r8: branchless gather — pointer-select against a ws zero-row instead of 16
// exec-masked loads; all 16 feature loads hoisted into one unconditional
// cluster (MLP 4 -> 20 outstanding/wave), stores drain on descending vmcnt.
#define NYv 496
#define NXv 432
#define Cv  64
#define Bv  4
#define PLANE (NYv * NXv)            // 214272 elements per (b,c) plane
#define NVEC (NXv / 4)               // 108 float4 vectors per canvas row
#define ROWS (Bv * NYv)              // 1984 canvas rows
#define UNITS (ROWS * NVEC)          // 214272 vec-units == 837 * 256 exactly
#define CSPLIT 4
#define CCHUNK (Cv / CSPLIT)         // 16 channels per gather thread
#define CANVAS_INTS (Bv * PLANE)     // 857088 ints = 3.43 MB

typedef float  f32x4 __attribute__((ext_vector_type(4)));
typedef int    i32x4 __attribute__((ext_vector_type(4)));

// K1: scatter pillar index i into canvas[(b*NY + y)*NX + x].
// Canvas pre-set to -1 (memset 0xFF) so unoccupied cells read <0.
// Also re-zeroes the 64-float zero-row (ws is 0xAA-poisoned every iter).
__global__ __launch_bounds__(256) void scatter_idx(const int4* __restrict__ coords,
                                                   int* __restrict__ canvas,
                                                   float* __restrict__ zerorow, int n) {
    int i = blockIdx.x * 256 + threadIdx.x;
    if (i < Cv) zerorow[i] = 0.0f;     // block 0 refreshes the zero row
    if (i >= n) return;
    int4 c4 = coords[i];               // (b, z, y, x)
    canvas[((size_t)c4.x * NYv + c4.z) * NXv + c4.w] = i;
}

// K2: inverse gather, full-lane exact-cover mapping (837*256 == 214272 units).
// Per thread: one int4 canvas load -> 4 pillar indices; per pillar ONE
// branchless base-pointer select (occupied -> its feature row, empty -> the
// L1-resident zero row), then 16 unconditional f32x4 loads issued as a single
// cluster, register-transposed into 16 coalesced float4 plane stores.
// No exec-mask regions -> scheduler hoists every load above every store.
__global__ __launch_bounds__(256) void gather_all(const float* __restrict__ feats,
                                                  const int* __restrict__ canvas,
                                                  const float* __restrict__ zerorow,
                                                  float* __restrict__ out) {
    int u = blockIdx.x * 256 + (int)threadIdx.x;   // 0..214271
    int g = u / NVEC;                              // canvas row 0..1983
    int v = u - g * NVEC;                          // 0..107
    int b = g / NYv;
    int y = g - b * NYv;
    int c0 = blockIdx.y * CCHUNK;

    i32x4 pi = *reinterpret_cast<const i32x4*>(canvas + (size_t)g * NXv + v * 4);
    int p[4] = {pi.x, pi.y, pi.z, pi.w};

    // Branchless base select: empty cells read the zero row (64 zero floats,
    // always L1-hit). c0 + cg*4 + 4 <= 64, so zerorow + c0 stays in bounds.
    const float* base[4];
#pragma unroll
    for (int j = 0; j < 4; ++j)
        base[j] = ((p[j] >= 0) ? (feats + (size_t)p[j] * Cv) : zerorow) + c0;

    // One unconditional load cluster: 16 outstanding dwordx4 per thread.
    f32x4 w[4][4];
#pragma unroll
    for (int cg = 0; cg < CCHUNK / 4; ++cg)
#pragma unroll
        for (int j = 0; j < 4; ++j)
            w[cg][j] = *reinterpret_cast<const f32x4*>(base[j] + cg * 4);

    float* outp = out + ((size_t)(b * Cv + c0)) * PLANE + y * NXv + v * 4;
#pragma unroll
    for (int cg = 0; cg < CCHUNK / 4; ++cg) {
#pragma unroll
        for (int k = 0; k < 4; ++k) {              // transpose: channel k of group
            f32x4 f;
            f.x = w[cg][0][k]; f.y = w[cg][1][k];
            f.z = w[cg][2][k]; f.w = w[cg][3][k];
            *reinterpret_cast<f32x4*>(outp + (size_t)(cg * 4 + k) * PLANE) = f;
        }
    }
}

extern "C" void kernel_launch(void* const* d_in, const int* in_sizes, int n_in,
                              void* d_out, int out_size, void* d_ws, size_t ws_size,
                              hipStream_t stream) {
    const float* feats  = (const float*)d_in[0];   // f32, [N, 64]
    const int*   coords = (const int*)d_in[1];     // int32, [N, 4]
    int n = in_sizes[0] / Cv;                      // 48000 pillars
    float* out    = (float*)d_out;
    int*   canvas = (int*)d_ws;                    // 3.43 MB of ~877 MB ws
    float* zerorow = (float*)((char*)d_ws + (size_t)CANVAS_INTS * sizeof(int));
    // zerorow offset 3,428,352 B — 16B-aligned.

    // -1 sentinel (0xAA poison is also negative, but don't rely on it).
    (void)hipMemsetAsync(canvas, 0xFF, (size_t)CANVAS_INTS * sizeof(int), stream);

    scatter_idx<<<(n + 255) / 256, 256, 0, stream>>>((const int4*)coords, canvas,
                                                     zerorow, n);

    dim3 gmain(UNITS / 256, CSPLIT);               // (837, 4) — exact cover
    gather_all<<<gmain, 256, 0, stream>>>(feats, canvas, zerorow, out);
}

// Round 2
// 229.139 us; speedup vs baseline: 1.0024x; 1.0017x over previous
//
#include <hip/hip_runtime.h>
#include <stdint.h>

// All buffers f32. Timed window carries ~164 us of harness poison fills
// (857 MB ws fill @ ~131 us + 219 MB out fill @ ~33 us, visible in rocprof
// every iteration); our 3 dispatches are the ~65 us remainder.
// Config history: r5 plain/CSPLIT4 = 231.0 | r4 = 233.6 | r7 nt/CSPLIT2 = 240.2
//   r8 branchless zero-row gather = 229.5 (neutral -> not load-latency-bound).
// r9: channel-split moved INSIDE the block (4 waves = 4 c-chunks per spatial
// slice). Previously the 4 blocks sharing canvas/feats lines were 837
// dispatch slots apart -> different XCDs -> 4x L2 replication of canvas
// (13.7 MB re-read) and pillar feature lines. Now they are 4 waves of ONE
// block: canvas int4s L1-broadcast, both 128B lines of a pillar row stay in
// one CU's L1. Store pattern per wave unchanged (1 KB contiguous per store).
#define NYv 496
#define NXv 432
#define Cv  64
#define Bv  4
#define PLANE (NYv * NXv)            // 214272 elements per (b,c) plane
#define NVEC (NXv / 4)               // 108 float4 vectors per canvas row
#define ROWS (Bv * NYv)              // 1984 canvas rows
#define UNITS (ROWS * NVEC)          // 214272 vec-units == 3348 * 64 exactly
#define CSPLIT 4                     // c-chunks, now = waves per block
#define CCHUNK (Cv / CSPLIT)         // 16 channels per gather thread
#define CANVAS_INTS (Bv * PLANE)     // 857088 ints = 3.43 MB

typedef float  f32x4 __attribute__((ext_vector_type(4)));
typedef int    i32x4 __attribute__((ext_vector_type(4)));

// K1: scatter pillar index i into canvas[(b*NY + y)*NX + x].
// Canvas pre-set to -1 (memset 0xFF) so unoccupied cells read <0.
// Also re-zeroes the 64-float zero-row (ws is poisoned every iter).
__global__ __launch_bounds__(256) void scatter_idx(const int4* __restrict__ coords,
                                                   int* __restrict__ canvas,
                                                   float* __restrict__ zerorow, int n) {
    int i = blockIdx.x * 256 + threadIdx.x;
    if (i < Cv) zerorow[i] = 0.0f;     // block 0 refreshes the zero row
    if (i >= n) return;
    int4 c4 = coords[i];               // (b, z, y, x)
    canvas[((size_t)c4.x * NYv + c4.z) * NXv + c4.w] = i;
}

// K2: inverse gather, exact cover: 3348 blocks x 64 lanes == 214272 units,
// 4 waves/block == 4 channel-chunks. Per thread: one int4 canvas load ->
// 4 pillar indices; branchless base-pointer select (empty -> L1-resident
// zero row); 16 unconditional f32x4 loads register-transposed into 16
// coalesced float4 plane stores.
__global__ __launch_bounds__(256) void gather_all(const float* __restrict__ feats,
                                                  const int* __restrict__ canvas,
                                                  const float* __restrict__ zerorow,
                                                  float* __restrict__ out) {
    int lane = (int)threadIdx.x & 63;
    int u = blockIdx.x * 64 + lane;                // 0..214271 (spatial vec-unit)
    int c0 = ((int)threadIdx.x >> 6) * CCHUNK;     // wave id -> channel chunk
    int g = u / NVEC;                              // canvas row 0..1983
    int v = u - g * NVEC;                          // 0..107
    int b = g / NYv;
    int y = g - b * NYv;

    i32x4 pi = *reinterpret_cast<const i32x4*>(canvas + (size_t)g * NXv + v * 4);
    int p[4] = {pi.x, pi.y, pi.z, pi.w};

    // Branchless base select: empty cells read the zero row (64 zero floats,
    // always cache-hit). c0 + cg*4 + 4 <= 64, so zerorow + c0 stays in bounds.
    const float* base[4];
#pragma unroll
    for (int j = 0; j < 4; ++j)
        base[j] = ((p[j] >= 0) ? (feats + (size_t)p[j] * Cv) : zerorow) + c0;

    // One unconditional load cluster: 16 outstanding dwordx4 per thread.
    f32x4 w[4][4];
#pragma unroll
    for (int cg = 0; cg < CCHUNK / 4; ++cg)
#pragma unroll
        for (int j = 0; j < 4; ++j)
            w[cg][j] = *reinterpret_cast<const f32x4*>(base[j] + cg * 4);

    float* outp = out + ((size_t)(b * Cv + c0)) * PLANE + y * NXv + v * 4;
#pragma unroll
    for (int cg = 0; cg < CCHUNK / 4; ++cg) {
#pragma unroll
        for (int k = 0; k < 4; ++k) {              // transpose: channel k of group
            f32x4 f;
            f.x = w[cg][0][k]; f.y = w[cg][1][k];
            f.z = w[cg][2][k]; f.w = w[cg][3][k];
            *reinterpret_cast<f32x4*>(outp + (size_t)(cg * 4 + k) * PLANE) = f;
        }
    }
}

extern "C" void kernel_launch(void* const* d_in, const int* in_sizes, int n_in,
                              void* d_out, int out_size, void* d_ws, size_t ws_size,
                              hipStream_t stream) {
    const float* feats  = (const float*)d_in[0];   // f32, [N, 64]
    const int*   coords = (const int*)d_in[1];     // int32, [N, 4]
    int n = in_sizes[0] / Cv;                      // 48000 pillars
    float* out    = (float*)d_out;
    int*   canvas = (int*)d_ws;                    // 3.43 MB of ~877 MB ws
    float* zerorow = (float*)((char*)d_ws + (size_t)CANVAS_INTS * sizeof(int));
    // zerorow offset 3,428,352 B — 16B-aligned.

    // -1 sentinel (0xAA poison is also negative, but don't rely on it).
    (void)hipMemsetAsync(canvas, 0xFF, (size_t)CANVAS_INTS * sizeof(int), stream);

    scatter_idx<<<(n + 255) / 256, 256, 0, stream>>>((const int4*)coords, canvas,
                                                     zerorow, n);

    gather_all<<<UNITS / 64, 256, 0, stream>>>(feats, canvas, zerorow, out);
}